// Round 16
// baseline (142.502 us; speedup 1.0000x reference)
//
#include <hip/hip_runtime.h>

// B=256, L=8192, C=8. real: one-hot f32 [B,L,C]; pred: uniform f32 [B,L,C].
// Scalar f32 output: 0.5*(1-argmax_acc) + 0.5*(1-exactmatch_acc).
//
// R16: roofline probe. R3/R12/R15 (VGPR burst / 4-slot pipeline / LDS DMA)
// all pin at 43-45us = 3.1 TB/s effective read; fillBuffer writes 6.5 TB/s.
// Last unexplored axis: max TLP. 8192 blocks x 256 thr = 1 position/thread,
// 4 plain dwordx4 loads, minimal VGPR (~20) -> up to 32 waves/CU resident.
// Pre-commit: 42-46us => ROOFLINE; <40us => iterate on occupancy.

#define BLOCKS   8192
#define THREADS  256
#define NPOS     (256 * 8192)              // 2097152 positions = BLOCKS*THREADS

__global__ __launch_bounds__(THREADS) void ss_acc_loss_main(
    const float* __restrict__ real,
    const float* __restrict__ pred,
    unsigned int* __restrict__ partial)   // [BLOCKS] packed: arg | exact<<16
{
    const int tid = blockIdx.x * THREADS + threadIdx.x;   // == position index
    const float4* __restrict__ r4 = reinterpret_cast<const float4*>(real);
    const float4* __restrict__ p4 = reinterpret_cast<const float4*>(pred);

    const size_t k = 2 * (size_t)tid;
    float4 r0 = r4[k], r1 = r4[k + 1];
    float4 p0 = p4[k], p1 = p4[k + 1];

    float r[8] = {r0.x, r0.y, r0.z, r0.w, r1.x, r1.y, r1.z, r1.w};
    float p[8] = {p0.x, p0.y, p0.z, p0.w, p1.x, p1.y, p1.z, p1.w};
    int   ta = 0, pa = 0;
    float tm = r[0], pm = p[0];
    bool  ex = true;
    #pragma unroll
    for (int kk = 0; kk < 8; ++kk) {
        if (r[kk] > tm) { tm = r[kk]; ta = kk; }   // first-occurrence argmax
        if (p[kk] > pm) { pm = p[kk]; pa = kk; }
        ex = ex && (r[kk] == ((p[kk] > 0.5f) ? 1.0f : 0.0f));  // real is exactly 0/1
    }
    unsigned int val = (unsigned int)(pa == ta) | ((unsigned int)ex << 16);
    // block sums <= 256 per field -> no overflow in 16-bit packing.

    #pragma unroll
    for (int off = 32; off > 0; off >>= 1)
        val += __shfl_down(val, off, 64);

    __shared__ unsigned int s[4];
    const int wave = threadIdx.x >> 6;
    const int lane = threadIdx.x & 63;
    if (lane == 0) s[wave] = val;
    __syncthreads();

    if (threadIdx.x == 0)
        partial[blockIdx.x] = s[0] + s[1] + s[2] + s[3];   // plain store, no atomics
}

__global__ __launch_bounds__(256) void ss_acc_loss_finalize(
    const unsigned int* __restrict__ partial,
    float* __restrict__ out)
{
    const int t = threadIdx.x;
    unsigned int a = 0, e = 0;
    #pragma unroll
    for (int j = 0; j < 32; ++j) {           // 8192 partials = 32 * 256, coalesced
        unsigned int v = partial[j * 256 + t];
        a += v & 0xFFFFu;
        e += v >> 16;
    }
    #pragma unroll
    for (int off = 32; off > 0; off >>= 1) {
        a += __shfl_down(a, off, 64);
        e += __shfl_down(e, off, 64);
    }
    __shared__ unsigned int sa[4], se[4];
    const int wave = t >> 6, lane = t & 63;
    if (lane == 0) { sa[wave] = a; se[wave] = e; }
    __syncthreads();
    if (t == 0) {
        unsigned int c0 = sa[0] + sa[1] + sa[2] + sa[3];
        unsigned int c1 = se[0] + se[1] + se[2] + se[3];
        const float inv_n = 1.0f / (float)NPOS;   // 2^21 -> exact
        out[0] = 0.5f * (1.0f - (float)c0 * inv_n)
               + 0.5f * (1.0f - (float)c1 * inv_n);
    }
}

extern "C" void kernel_launch(void* const* d_in, const int* in_sizes, int n_in,
                              void* d_out, int out_size, void* d_ws, size_t ws_size,
                              hipStream_t stream) {
    const float* real     = (const float*)d_in[0];
    const float* pred     = (const float*)d_in[1];
    unsigned int* partial = (unsigned int*)d_ws;   // fully overwritten, no init needed
    float* out            = (float*)d_out;

    ss_acc_loss_main<<<BLOCKS, THREADS, 0, stream>>>(real, pred, partial);
    ss_acc_loss_finalize<<<1, 256, 0, stream>>>(partial, out);
}